// Round 12
// baseline (833.410 us; speedup 1.0000x reference)
//
#include <hip/hip_runtime.h>

#define NN 50000
#define NE 800000
#define DD 128
#define ED 32
#define NL 4
#define BN_EPS 1e-5f
#define SCAN_B 1024
#define NB ((NN + SCAN_B - 1) / SCAN_B)   // 49
#define EB 128                            // edges per block (edge kernel)
#define MR 32                             // rows per tile (mlp kernel)
#define MLP_GRID 1280                     // persistent blocks (5/CU x 256 CU)

typedef __attribute__((ext_vector_type(8))) short bf16x8;
typedef __attribute__((ext_vector_type(4))) float f32x4;

__device__ __forceinline__ unsigned short f2bf(float f) {
    unsigned u = __float_as_uint(f);
    u += 0x7fffu + ((u >> 16) & 1u);
    return (unsigned short)(u >> 16);
}
__device__ __forceinline__ float bf2f(unsigned short h) {
    return __uint_as_float((unsigned)h << 16);
}

// ---------------- CSR build ----------------
__global__ __launch_bounds__(256) void hist_kernel(
    const int* __restrict__ edst, int* __restrict__ deg)
{
    const int e = blockIdx.x * 256 + threadIdx.x;
    if (e < NE) atomicAdd(&deg[edst[e]], 1);
}

__global__ __launch_bounds__(256) void scan1_kernel(
    const int* __restrict__ deg, int* __restrict__ rowptr, int* __restrict__ bsum)
{
    __shared__ int sh[256];
    const int t = threadIdx.x, b = blockIdx.x;
    const int base = b * SCAN_B + t * 4;
    int v[4];
#pragma unroll
    for (int j = 0; j < 4; ++j) {
        const int idx = base + j;
        v[j] = (idx < NN) ? deg[idx] : 0;
    }
    sh[t] = v[0] + v[1] + v[2] + v[3];
    __syncthreads();
    for (int off = 1; off < 256; off <<= 1) {
        const int val = (t >= off) ? sh[t - off] : 0;
        __syncthreads();
        sh[t] += val;
        __syncthreads();
    }
    int p = (t == 0) ? 0 : sh[t - 1];
#pragma unroll
    for (int j = 0; j < 4; ++j) {
        const int idx = base + j;
        if (idx < NN) rowptr[idx] = p;
        p += v[j];
    }
    if (t == 255) bsum[b] = sh[255];
}

__global__ void scan2_kernel(int* __restrict__ bsum)
{
    if (threadIdx.x == 0) {
        int acc = 0;
        for (int i = 0; i < NB; ++i) { const int v = bsum[i]; bsum[i] = acc; acc += v; }
    }
}

__global__ __launch_bounds__(256) void scan3_kernel(
    int* __restrict__ rowptr, int* __restrict__ cursor, const int* __restrict__ bsum)
{
    const int idx = blockIdx.x * 256 + threadIdx.x;
    if (idx < NN) {
        const int v = rowptr[idx] + bsum[idx / SCAN_B];
        rowptr[idx] = v;
        cursor[idx] = v;
    }
    if (idx == 0) rowptr[NN] = NE;
}

// scatter only the edge-id permutation (4B scattered writes — minimal RMW amp)
__global__ __launch_bounds__(256) void scatter_idx_kernel(
    const int* __restrict__ edst, int* __restrict__ cursor, int* __restrict__ eid_perm)
{
    const int e = blockIdx.x * 256 + threadIdx.x;
    if (e < NE) {
        const int pos = atomicAdd(&cursor[edst[e]], 1);
        eid_perm[pos] = e;
    }
}

// per sorted position (8 lanes/edge): fill (src,dst) + gather ea row -> bf16.
__global__ __launch_bounds__(256) void sdea_kernel(
    const int* __restrict__ eid_perm, const int* __restrict__ esrc,
    const int* __restrict__ edst, const float* __restrict__ ea,
    int2* __restrict__ sd_perm, unsigned short* __restrict__ ea_bf)
{
    const int tid = blockIdx.x * 256 + threadIdx.x;
    const int pos = tid >> 3, j = tid & 7;
    if (pos < NE) {
        const int e = eid_perm[pos];
        if (j == 0) sd_perm[pos] = make_int2(esrc[e], edst[e]);
        const float4 v = *(const float4*)&ea[(size_t)e * ED + j * 4];
        uint2 p;
        p.x = (unsigned)f2bf(v.x) | ((unsigned)f2bf(v.y) << 16);
        p.y = (unsigned)f2bf(v.z) | ((unsigned)f2bf(v.w) << 16);
        *(uint2*)&ea_bf[(size_t)pos * ED + j * 4] = p;
    }
    if (tid == 0) sd_perm[NE] = make_int2(0, -1);   // sentinel for window-end test
}

// x0 f32 -> bf16 (once per call, feeds layer 0)
__global__ __launch_bounds__(256) void x0conv_kernel(
    const float* __restrict__ x0, unsigned short* __restrict__ xbf)
{
    const size_t i = ((size_t)blockIdx.x * 256 + threadIdx.x) * 8;
    if (i >= (size_t)NN * DD) return;
    const float4 a = *(const float4*)&x0[i];
    const float4 b = *(const float4*)&x0[i + 4];
    uint4 o;
    o.x = (unsigned)f2bf(a.x) | ((unsigned)f2bf(a.y) << 16);
    o.y = (unsigned)f2bf(a.z) | ((unsigned)f2bf(a.w) << 16);
    o.z = (unsigned)f2bf(b.x) | ((unsigned)f2bf(b.y) << 16);
    o.w = (unsigned)f2bf(b.z) | ((unsigned)f2bf(b.w) << 16);
    *(uint4*)&xbf[i] = o;
}

// W_edge [NL][ED][DD] f32 -> wtb bf16 [NL][DD][ED] (transposed, contiguous in K)
__global__ __launch_bounds__(256) void wconv_kernel(
    const float* __restrict__ We, unsigned short* __restrict__ wtb)
{
    const int tid = blockIdx.x * 256 + threadIdx.x;
    if (tid < NL * DD * ED) {
        const int l = tid / (DD * ED);
        const int r = tid % (DD * ED);
        const int c = r / ED, k = r % ED;
        wtb[tid] = f2bf(We[(size_t)l * ED * DD + k * DD + c]);
    }
}

// W1/W2 [NL][DD][DD] f32 ([k][n]) -> bf16 [NL][DD][DD] ([n][k])
__global__ __launch_bounds__(256) void w12conv_kernel(
    const float* __restrict__ W1, const float* __restrict__ W2,
    unsigned short* __restrict__ w1t, unsigned short* __restrict__ w2t)
{
    const int tid = blockIdx.x * 256 + threadIdx.x;
    if (tid < NL * DD * DD) {
        const int l = tid / (DD * DD);
        const int r = tid % (DD * DD);
        const int n = r / DD, k = r % DD;
        const size_t s = (size_t)l * DD * DD + k * DD + n;
        w1t[tid] = f2bf(W1[s]);
        w2t[tid] = f2bf(W2[s]);
    }
}

// ---------------- MFMA edge kernel ----------------
// EB=128 edges/block, 4 waves, 32 KB LDS. Phase C: full 32-window load hoist
// (R8 structure) + carried acc/seg across the window (R7 flush semantics).
__global__ __launch_bounds__(256, 4) void edge_mfma_kernel(
    const unsigned short* __restrict__ xbf,   // [NN][DD] bf16
    const unsigned short* __restrict__ eab,   // [NE][ED] bf16, dst-sorted
    const int2* __restrict__ sd_perm,         // [NE+1] (src,dst), dst-sorted
    const unsigned short* __restrict__ wtb,   // [DD][ED] bf16 (layer slice)
    const float* __restrict__ be,
    float* __restrict__ agg)
{
    __shared__ unsigned short msgl[EB * 128];   // 32 KB
    const int t = threadIdx.x;
    const int wv = t >> 6, ln = t & 63;
    const int l15 = ln & 15, kb = ln >> 4;

    // XCD swizzle (nwg = NE/EB = 6250, bijective m204 form) — neutral but free
    const int nwg = NE / EB;
    const int q = nwg >> 3, r = nwg & 7;
    const int xcd = blockIdx.x & 7, seq = blockIdx.x >> 3;
    const int wg = (xcd < r ? xcd * (q + 1) : r * (q + 1) + (xcd - r) * q) + seq;
    const int e0 = wg * EB;

    const int c0 = (2 * wv + 0) * 16 + l15;
    const int c1 = (2 * wv + 1) * 16 + l15;
    const bf16x8 bfr0 = *(const bf16x8*)&wtb[c0 * ED + kb * 8];
    const bf16x8 bfr1 = *(const bf16x8*)&wtb[c1 * ED + kb * 8];

#pragma unroll
    for (int eg = 0; eg < EB / 16; ++eg) {
        const int edge = eg * 16 + l15;
        const bf16x8 afr = *(const bf16x8*)&eab[(size_t)(e0 + edge) * ED + kb * 8];
        f32x4 z = {0.f, 0.f, 0.f, 0.f};
        const f32x4 d0 = __builtin_amdgcn_mfma_f32_16x16x32_bf16(afr, bfr0, z, 0, 0, 0);
        const f32x4 d1 = __builtin_amdgcn_mfma_f32_16x16x32_bf16(afr, bfr1, z, 0, 0, 0);
#pragma unroll
        for (int j = 0; j < 4; ++j) {
            const int mrow = eg * 16 + kb * 4 + j;
            const int sw = ((mrow >> 2) & 3) << 3;
            const int i0 = (((c0 >> 1) ^ sw) << 1) | (c0 & 1);
            const int i1 = (((c1 >> 1) ^ sw) << 1) | (c1 & 1);
            msgl[mrow * 128 + i0] = f2bf(d0[j]);
            msgl[mrow * 128 + i1] = f2bf(d1[j]);
        }
    }
    __syncthreads();

    // Phase C: all loads hoisted, single carried accumulation chain.
    const int lbase = wv * 32;
    const int2* sdp = &sd_perm[e0 + lbase];
    const int c2 = ln * 2;
    const float2 bv = *(const float2*)&be[c2];

    int4 pr[16];
#pragma unroll
    for (int q2 = 0; q2 < 16; ++q2)
        pr[q2] = *(const int4*)&sdp[2 * q2];
    int dsts[33];
#pragma unroll
    for (int q2 = 0; q2 < 16; ++q2) {
        dsts[2 * q2]     = pr[q2].y;
        dsts[2 * q2 + 1] = pr[q2].w;
    }
    dsts[32] = sdp[32].y;   // sentinel-backed
    unsigned xu[32];
#pragma unroll
    for (int q2 = 0; q2 < 16; ++q2) {
        xu[2 * q2]     = *(const unsigned*)&xbf[(size_t)pr[q2].x * DD + c2];
        xu[2 * q2 + 1] = *(const unsigned*)&xbf[(size_t)pr[q2].z * DD + c2];
    }

    float2 acc = {0.f, 0.f};
    int seg_start = 0;   // carried across the whole 32-edge window
#pragma unroll
    for (int i = 0; i < 32; ++i) {
        const int dw = ln ^ (((i >> 2) & 3) << 3);
        const unsigned mm = *(const unsigned*)&msgl[(lbase + i) * 128 + dw * 2];
        const float mlo = __uint_as_float(mm << 16);
        const float mhi = __uint_as_float(mm & 0xffff0000u);
        acc.x += fmaxf(__uint_as_float(xu[i] << 16) + mlo + bv.x, 0.f);
        acc.y += fmaxf(__uint_as_float(xu[i] & 0xffff0000u) + mhi + bv.y, 0.f);
        if (i == 31 || dsts[i + 1] != dsts[i]) {
            float* ap = &agg[(size_t)dsts[i] * DD + c2];
            if (seg_start > 0 && i < 31) {
                *(float2*)ap = acc;             // interior: sole writer
            } else {
                unsafeAtomicAdd(ap + 0, acc.x); // chunk-boundary segment
                unsafeAtomicAdd(ap + 1, acc.y);
            }
            acc.x = 0.f; acc.y = 0.f;
            seg_start = i + 1;
        }
    }
}

// ---------------- MFMA node MLP kernel (persistent grid-stride) ----------------
// MR=32 rows/tile, 4 waves, 24 KB LDS. Weights + biases hoisted out of the
// tile loop (loaded once per block instead of once per tile); no tail wave.
__global__ __launch_bounds__(256, 5) void mlp_mfma_kernel(
    const unsigned short* __restrict__ xbf, const float* __restrict__ agg,
    float* __restrict__ h2out,
    const unsigned short* __restrict__ w1t,   // [DD][DD] bf16 [n][k] (layer slice)
    const unsigned short* __restrict__ w2t,
    const float* __restrict__ b1, const float* __restrict__ b2,
    float* __restrict__ bns)
{
    __shared__ unsigned short ah[MR * 128];  // 8 KB h hi
    __shared__ unsigned short al[MR * 128];  // 8 KB h lo
    __shared__ unsigned short bh[MR * 128];  // 8 KB h1
    const int t = threadIdx.x;
    const int wv = t >> 6, ln = t & 63, l15 = ln & 15, kb = ln >> 4;

    // hoisted: weight fragments + biases (reused across all tiles)
    bf16x8 w1f[2][4], w2f[2][4];
#pragma unroll
    for (int nt = 0; nt < 2; ++nt) {
        const int n = wv * 32 + nt * 16 + l15;
#pragma unroll
        for (int ks = 0; ks < 4; ++ks) {
            w1f[nt][ks] = *(const bf16x8*)&w1t[n * DD + ks * 32 + kb * 8];
            w2f[nt][ks] = *(const bf16x8*)&w2t[n * DD + ks * 32 + kb * 8];
        }
    }
    const int cA = wv * 32 + l15, cB = wv * 32 + 16 + l15;
    const float b1v[2] = {b1[cA], b1[cB]};
    const float b2v[2] = {b2[cA], b2[cB]};

    const int NT = (NN + MR - 1) / MR;
    for (int tile = blockIdx.x; tile < NT; tile += gridDim.x) {
        const int r0 = tile * MR;

        // ---- stage h = x + agg -> split bf16, swizzled ----
#pragma unroll
        for (int p = 0; p < 2; ++p) {
            const int row = p * 16 + (t >> 4);
            const int gc = t & 15;
            const int grow = r0 + row;
            float v[8] = {0.f, 0.f, 0.f, 0.f, 0.f, 0.f, 0.f, 0.f};
            if (grow < NN) {
                const size_t g = (size_t)grow * DD + gc * 8;
                const uint4 xu = *(const uint4*)&xbf[g];
                const float4 ga = *(const float4*)&agg[g];
                const float4 gb4 = *(const float4*)&agg[g + 4];
                v[0] = __uint_as_float(xu.x << 16)          + ga.x;
                v[1] = __uint_as_float(xu.x & 0xffff0000u)  + ga.y;
                v[2] = __uint_as_float(xu.y << 16)          + ga.z;
                v[3] = __uint_as_float(xu.y & 0xffff0000u)  + ga.w;
                v[4] = __uint_as_float(xu.z << 16)          + gb4.x;
                v[5] = __uint_as_float(xu.z & 0xffff0000u)  + gb4.y;
                v[6] = __uint_as_float(xu.w << 16)          + gb4.z;
                v[7] = __uint_as_float(xu.w & 0xffff0000u)  + gb4.w;
            }
            unsigned hiw[4], low[4];
#pragma unroll
            for (int j = 0; j < 4; ++j) {
                const unsigned short h0 = f2bf(v[2 * j]);
                const unsigned short h1 = f2bf(v[2 * j + 1]);
                const unsigned short q0 = f2bf(v[2 * j] - bf2f(h0));
                const unsigned short q1 = f2bf(v[2 * j + 1] - bf2f(h1));
                hiw[j] = (unsigned)h0 | ((unsigned)h1 << 16);
                low[j] = (unsigned)q0 | ((unsigned)q1 << 16);
            }
            const int off = row * 128 + (gc ^ (row & 7)) * 8;
            *(uint4*)&ah[off] = *(uint4*)hiw;
            *(uint4*)&al[off] = *(uint4*)low;
        }
        __syncthreads();   // staging visible; also fences prior iter's GEMM2 bh reads

        // ---- GEMM1 (split hi+lo) ----
        f32x4 acc[2][2];
#pragma unroll
        for (int mt = 0; mt < 2; ++mt)
#pragma unroll
            for (int nt = 0; nt < 2; ++nt)
                acc[mt][nt] = (f32x4){0.f, 0.f, 0.f, 0.f};
#pragma unroll
        for (int ks = 0; ks < 4; ++ks) {
#pragma unroll
            for (int mt = 0; mt < 2; ++mt) {
                const int row = mt * 16 + l15;
                const int off = row * 128 + ((ks * 4 + kb) ^ (row & 7)) * 8;
                const bf16x8 afh = *(const bf16x8*)&ah[off];
                const bf16x8 afl = *(const bf16x8*)&al[off];
#pragma unroll
                for (int nt = 0; nt < 2; ++nt) {
                    acc[mt][nt] = __builtin_amdgcn_mfma_f32_16x16x32_bf16(afh, w1f[nt][ks], acc[mt][nt], 0, 0, 0);
                    acc[mt][nt] = __builtin_amdgcn_mfma_f32_16x16x32_bf16(afl, w1f[nt][ks], acc[mt][nt], 0, 0, 0);
                }
            }
        }

        // ---- h1 = relu(acc + b1) -> bf16 LDS (hi only) ----
#pragma unroll
        for (int mt = 0; mt < 2; ++mt) {
#pragma unroll
            for (int nt = 0; nt < 2; ++nt) {
                const int col = wv * 32 + nt * 16 + l15;
#pragma unroll
                for (int j = 0; j < 4; ++j) {
                    const int row = mt * 16 + kb * 4 + j;
                    const float v = fmaxf(acc[mt][nt][j] + b1v[nt], 0.f);
                    const int off = row * 128 + ((col >> 3) ^ (row & 7)) * 8 + (col & 7);
                    bh[off] = f2bf(v);
                }
            }
        }
        __syncthreads();

        // ---- GEMM2 (hi only) ----
#pragma unroll
        for (int mt = 0; mt < 2; ++mt)
#pragma unroll
            for (int nt = 0; nt < 2; ++nt)
                acc[mt][nt] = (f32x4){0.f, 0.f, 0.f, 0.f};
#pragma unroll
        for (int ks = 0; ks < 4; ++ks) {
#pragma unroll
            for (int mt = 0; mt < 2; ++mt) {
                const int row = mt * 16 + l15;
                const int off = row * 128 + ((ks * 4 + kb) ^ (row & 7)) * 8;
                const bf16x8 afh = *(const bf16x8*)&bh[off];
#pragma unroll
                for (int nt = 0; nt < 2; ++nt)
                    acc[mt][nt] = __builtin_amdgcn_mfma_f32_16x16x32_bf16(afh, w2f[nt][ks], acc[mt][nt], 0, 0, 0);
            }
        }

        // ---- epilogue: h2 store + BN partial sums ----
        float ps[2] = {0.f, 0.f}, pq[2] = {0.f, 0.f};
#pragma unroll
        for (int mt = 0; mt < 2; ++mt) {
#pragma unroll
            for (int nt = 0; nt < 2; ++nt) {
                const int col = wv * 32 + nt * 16 + l15;
#pragma unroll
                for (int j = 0; j < 4; ++j) {
                    const int row = r0 + mt * 16 + kb * 4 + j;
                    const float v = acc[mt][nt][j] + b2v[nt];
                    if (row < NN) {
                        h2out[(size_t)row * DD + col] = v;
                        ps[nt] += v;
                        pq[nt] += v * v;
                    }
                }
            }
        }
#pragma unroll
        for (int nt = 0; nt < 2; ++nt) {
            ps[nt] += __shfl_xor(ps[nt], 16);
            ps[nt] += __shfl_xor(ps[nt], 32);
            pq[nt] += __shfl_xor(pq[nt], 16);
            pq[nt] += __shfl_xor(pq[nt], 32);
        }
        if (kb == 0) {
#pragma unroll
            for (int nt = 0; nt < 2; ++nt) {
                const int col = wv * 32 + nt * 16 + l15;
                unsafeAtomicAdd(&bns[col], ps[nt]);
                unsafeAtomicAdd(&bns[DD + col], pq[nt]);
            }
        }
    }
}

// ---------------- BN apply + ReLU -> bf16 x; also zeroes agg for next layer ----------------
__global__ __launch_bounds__(256) void bn_apply_bf16(
    float* __restrict__ h2, const float* __restrict__ bns,
    const float* __restrict__ gamma, const float* __restrict__ beta,
    unsigned short* __restrict__ xout)
{
    const size_t i = ((size_t)blockIdx.x * 256 + threadIdx.x) * 4;
    if (i >= (size_t)NN * DD) return;
    const int c4 = (int)(i & 127);
    const float4 hv = *(const float4*)&h2[i];
    const float4 sv = *(const float4*)&bns[c4];
    const float4 qv = *(const float4*)&bns[DD + c4];
    const float4 gv = *(const float4*)&gamma[c4];
    const float4 bv = *(const float4*)&beta[c4];
    const float inv_n = 1.f / (float)NN;
    float o0, o1, o2, o3;
    { const float m = sv.x * inv_n; const float var = qv.x * inv_n - m * m;
      o0 = fmaxf((hv.x - m) * __frsqrt_rn(var + BN_EPS) * gv.x + bv.x, 0.f); }
    { const float m = sv.y * inv_n; const float var = qv.y * inv_n - m * m;
      o1 = fmaxf((hv.y - m) * __frsqrt_rn(var + BN_EPS) * gv.y + bv.y, 0.f); }
    { const float m = sv.z * inv_n; const float var = qv.z * inv_n - m * m;
      o2 = fmaxf((hv.z - m) * __frsqrt_rn(var + BN_EPS) * gv.z + bv.z, 0.f); }
    { const float m = sv.w * inv_n; const float var = qv.w * inv_n - m * m;
      o3 = fmaxf((hv.w - m) * __frsqrt_rn(var + BN_EPS) * gv.w + bv.w, 0.f); }
    uint2 o;
    o.x = (unsigned)f2bf(o0) | ((unsigned)f2bf(o1) << 16);
    o.y = (unsigned)f2bf(o2) | ((unsigned)f2bf(o3) << 16);
    *(uint2*)&xout[i] = o;
    *(float4*)&h2[i] = (float4){0.f, 0.f, 0.f, 0.f};   // fused agg zeroing
}

// ---------------- BN apply + ReLU -> f32 out (final layer) ----------------
__global__ __launch_bounds__(256) void bn_apply_f32(
    const float* __restrict__ h2, const float* __restrict__ bns,
    const float* __restrict__ gamma, const float* __restrict__ beta,
    float* __restrict__ xout)
{
    const size_t i = ((size_t)blockIdx.x * 256 + threadIdx.x) * 4;
    if (i >= (size_t)NN * DD) return;
    const int c4 = (int)(i & 127);
    const float4 hv = *(const float4*)&h2[i];
    const float4 sv = *(const float4*)&bns[c4];
    const float4 qv = *(const float4*)&bns[DD + c4];
    const float4 gv = *(const float4*)&gamma[c4];
    const float4 bv = *(const float4*)&beta[c4];
    const float inv_n = 1.f / (float)NN;
    float4 ov;
    { const float m = sv.x * inv_n; const float var = qv.x * inv_n - m * m;
      ov.x = fmaxf((hv.x - m) * __frsqrt_rn(var + BN_EPS) * gv.x + bv.x, 0.f); }
    { const float m = sv.y * inv_n; const float var = qv.y * inv_n - m * m;
      ov.y = fmaxf((hv.y - m) * __frsqrt_rn(var + BN_EPS) * gv.y + bv.y, 0.f); }
    { const float m = sv.z * inv_n; const float var = qv.z * inv_n - m * m;
      ov.z = fmaxf((hv.z - m) * __frsqrt_rn(var + BN_EPS) * gv.z + bv.z, 0.f); }
    { const float m = sv.w * inv_n; const float var = qv.w * inv_n - m * m;
      ov.w = fmaxf((hv.w - m) * __frsqrt_rn(var + BN_EPS) * gv.w + bv.w, 0.f); }
    *(float4*)&xout[i] = ov;
}

extern "C" void kernel_launch(void* const* d_in, const int* in_sizes, int n_in,
                              void* d_out, int out_size, void* d_ws, size_t ws_size,
                              hipStream_t stream) {
    const float* x0    = (const float*)d_in[0];
    const float* ea    = (const float*)d_in[1];
    const int*   eidx  = (const int*)d_in[2];
    const float* We    = (const float*)d_in[3];
    const float* be    = (const float*)d_in[4];
    const float* W1    = (const float*)d_in[5];
    const float* b1    = (const float*)d_in[6];
    const float* W2    = (const float*)d_in[7];
    const float* b2    = (const float*)d_in[8];
    const float* gamma = (const float*)d_in[9];
    const float* beta  = (const float*)d_in[10];
    float* out = (float*)d_out;
    float* ws  = (float*)d_ws;

    float* agg = ws;                              // NN*DD f32 (doubles as h2)
    float* bns = agg + (size_t)NN * DD;           // NL*256
    int* deg      = (int*)(bns + NL * 256);       // 50000
    int* rowptr   = deg + 50000;                  // 50004 (padded)
    int* cursor   = rowptr + 50004;               // 50000
    int* bsum     = cursor + 50000;               // 64
    int2* sd_perm = (int2*)(bsum + 64);           // NE+1 int2 (sentinel)
    int* eid_perm = (int*)(sd_perm + NE + 2);     // NE
    unsigned short* ea_bf = (unsigned short*)(eid_perm + NE);  // NE*ED
    unsigned short* wt_bf = ea_bf + (size_t)NE * ED;           // NL*DD*ED
    unsigned short* w1t   = wt_bf + (size_t)NL * DD * ED;      // NL*DD*DD
    unsigned short* w2t   = w1t + (size_t)NL * DD * DD;        // NL*DD*DD
    unsigned short* xbf   = w2t + (size_t)NL * DD * DD;        // NN*DD bf16

    const int* esrc = eidx;
    const int* edst = eidx + NE;

    // ---- CSR build + bf16 pre-conversion (once; reused by all 4 layers) ----
    hipMemsetAsync(deg, 0, NN * sizeof(int), stream);
    hipMemsetAsync(bns, 0, NL * 256 * sizeof(float), stream);
    hipMemsetAsync(agg, 0, (size_t)NN * DD * sizeof(float), stream);
    hist_kernel<<<(NE + 255) / 256, 256, 0, stream>>>(edst, deg);
    scan1_kernel<<<NB, 256, 0, stream>>>(deg, rowptr, bsum);
    scan2_kernel<<<1, 64, 0, stream>>>(bsum);
    scan3_kernel<<<(NN + 255) / 256, 256, 0, stream>>>(rowptr, cursor, bsum);
    scatter_idx_kernel<<<(NE + 255) / 256, 256, 0, stream>>>(edst, cursor, eid_perm);
    sdea_kernel<<<((size_t)NE * 8 + 255) / 256, 256, 0, stream>>>(
        eid_perm, esrc, edst, ea, sd_perm, ea_bf);
    x0conv_kernel<<<((NN * DD / 8) + 255) / 256, 256, 0, stream>>>(x0, xbf);
    wconv_kernel<<<(NL * DD * ED + 255) / 256, 256, 0, stream>>>(We, wt_bf);
    w12conv_kernel<<<(NL * DD * DD + 255) / 256, 256, 0, stream>>>(W1, W2, w1t, w2t);

    for (int l = 0; l < NL; ++l) {
        edge_mfma_kernel<<<NE / EB, 256, 0, stream>>>(
            xbf, ea_bf, sd_perm,
            wt_bf + (size_t)l * DD * ED, be + (size_t)l * DD, agg);
        mlp_mfma_kernel<<<MLP_GRID, 256, 0, stream>>>(
            xbf, agg, agg,
            w1t + (size_t)l * DD * DD, w2t + (size_t)l * DD * DD,
            b1 + (size_t)l * DD, b2 + (size_t)l * DD, bns + l * 256);
        if (l < NL - 1) {
            bn_apply_bf16<<<(NN * DD / 4 + 255) / 256, 256, 0, stream>>>(
                agg, bns + l * 256, gamma + (size_t)l * DD, beta + (size_t)l * DD, xbf);
        } else {
            bn_apply_f32<<<(NN * DD / 4 + 255) / 256, 256, 0, stream>>>(
                agg, bns + l * 256, gamma + (size_t)l * DD, beta + (size_t)l * DD, out);
        }
    }
}

// Round 13
// 655.383 us; speedup vs baseline: 1.2716x; 1.2716x over previous
//
#include <hip/hip_runtime.h>

#define NN 50000
#define NE 800000
#define DD 128
#define ED 32
#define NL 4
#define BN_EPS 1e-5f
#define SCAN_B 1024
#define NB ((NN + SCAN_B - 1) / SCAN_B)   // 49
#define EB 128                            // edges per block (edge kernel)
#define MR 32                             // rows per block (mlp kernel)

typedef __attribute__((ext_vector_type(8))) short bf16x8;
typedef __attribute__((ext_vector_type(4))) float f32x4;

__device__ __forceinline__ unsigned short f2bf(float f) {
    unsigned u = __float_as_uint(f);
    u += 0x7fffu + ((u >> 16) & 1u);
    return (unsigned short)(u >> 16);
}
__device__ __forceinline__ float bf2f(unsigned short h) {
    return __uint_as_float((unsigned)h << 16);
}

// ---------------- CSR build ----------------
__global__ __launch_bounds__(256) void hist_kernel(
    const int* __restrict__ edst, int* __restrict__ deg)
{
    const int e = blockIdx.x * 256 + threadIdx.x;
    if (e < NE) atomicAdd(&deg[edst[e]], 1);
}

__global__ __launch_bounds__(256) void scan1_kernel(
    const int* __restrict__ deg, int* __restrict__ rowptr, int* __restrict__ bsum)
{
    __shared__ int sh[256];
    const int t = threadIdx.x, b = blockIdx.x;
    const int base = b * SCAN_B + t * 4;
    int v[4];
#pragma unroll
    for (int j = 0; j < 4; ++j) {
        const int idx = base + j;
        v[j] = (idx < NN) ? deg[idx] : 0;
    }
    sh[t] = v[0] + v[1] + v[2] + v[3];
    __syncthreads();
    for (int off = 1; off < 256; off <<= 1) {
        const int val = (t >= off) ? sh[t - off] : 0;
        __syncthreads();
        sh[t] += val;
        __syncthreads();
    }
    int p = (t == 0) ? 0 : sh[t - 1];
#pragma unroll
    for (int j = 0; j < 4; ++j) {
        const int idx = base + j;
        if (idx < NN) rowptr[idx] = p;
        p += v[j];
    }
    if (t == 255) bsum[b] = sh[255];
}

__global__ void scan2_kernel(int* __restrict__ bsum)
{
    if (threadIdx.x == 0) {
        int acc = 0;
        for (int i = 0; i < NB; ++i) { const int v = bsum[i]; bsum[i] = acc; acc += v; }
    }
}

__global__ __launch_bounds__(256) void scan3_kernel(
    int* __restrict__ rowptr, int* __restrict__ cursor, const int* __restrict__ bsum)
{
    const int idx = blockIdx.x * 256 + threadIdx.x;
    if (idx < NN) {
        const int v = rowptr[idx] + bsum[idx / SCAN_B];
        rowptr[idx] = v;
        cursor[idx] = v;
    }
    if (idx == 0) rowptr[NN] = NE;
}

// scatter only the edge-id permutation (4B scattered writes — minimal RMW amp)
__global__ __launch_bounds__(256) void scatter_idx_kernel(
    const int* __restrict__ edst, int* __restrict__ cursor, int* __restrict__ eid_perm)
{
    const int e = blockIdx.x * 256 + threadIdx.x;
    if (e < NE) {
        const int pos = atomicAdd(&cursor[edst[e]], 1);
        eid_perm[pos] = e;
    }
}

// per sorted position (8 lanes/edge): fill (src,dst) + gather ea row -> bf16.
__global__ __launch_bounds__(256) void sdea_kernel(
    const int* __restrict__ eid_perm, const int* __restrict__ esrc,
    const int* __restrict__ edst, const float* __restrict__ ea,
    int2* __restrict__ sd_perm, unsigned short* __restrict__ ea_bf)
{
    const int tid = blockIdx.x * 256 + threadIdx.x;
    const int pos = tid >> 3, j = tid & 7;
    if (pos < NE) {
        const int e = eid_perm[pos];
        if (j == 0) sd_perm[pos] = make_int2(esrc[e], edst[e]);
        const float4 v = *(const float4*)&ea[(size_t)e * ED + j * 4];
        uint2 p;
        p.x = (unsigned)f2bf(v.x) | ((unsigned)f2bf(v.y) << 16);
        p.y = (unsigned)f2bf(v.z) | ((unsigned)f2bf(v.w) << 16);
        *(uint2*)&ea_bf[(size_t)pos * ED + j * 4] = p;
    }
    if (tid == 0) sd_perm[NE] = make_int2(0, -1);   // sentinel for window-end test
}

// x0 f32 -> bf16 (once per call, feeds layer 0)
__global__ __launch_bounds__(256) void x0conv_kernel(
    const float* __restrict__ x0, unsigned short* __restrict__ xbf)
{
    const size_t i = ((size_t)blockIdx.x * 256 + threadIdx.x) * 8;
    if (i >= (size_t)NN * DD) return;
    const float4 a = *(const float4*)&x0[i];
    const float4 b = *(const float4*)&x0[i + 4];
    uint4 o;
    o.x = (unsigned)f2bf(a.x) | ((unsigned)f2bf(a.y) << 16);
    o.y = (unsigned)f2bf(a.z) | ((unsigned)f2bf(a.w) << 16);
    o.z = (unsigned)f2bf(b.x) | ((unsigned)f2bf(b.y) << 16);
    o.w = (unsigned)f2bf(b.z) | ((unsigned)f2bf(b.w) << 16);
    *(uint4*)&xbf[i] = o;
}

// W_edge [NL][ED][DD] f32 -> wtb bf16 [NL][DD][ED] (transposed, contiguous in K)
__global__ __launch_bounds__(256) void wconv_kernel(
    const float* __restrict__ We, unsigned short* __restrict__ wtb)
{
    const int tid = blockIdx.x * 256 + threadIdx.x;
    if (tid < NL * DD * ED) {
        const int l = tid / (DD * ED);
        const int r = tid % (DD * ED);
        const int c = r / ED, k = r % ED;
        wtb[tid] = f2bf(We[(size_t)l * ED * DD + k * DD + c]);
    }
}

// W1/W2 [NL][DD][DD] f32 ([k][n]) -> bf16 [NL][DD][DD] ([n][k])
__global__ __launch_bounds__(256) void w12conv_kernel(
    const float* __restrict__ W1, const float* __restrict__ W2,
    unsigned short* __restrict__ w1t, unsigned short* __restrict__ w2t)
{
    const int tid = blockIdx.x * 256 + threadIdx.x;
    if (tid < NL * DD * DD) {
        const int l = tid / (DD * DD);
        const int r = tid % (DD * DD);
        const int n = r / DD, k = r % DD;
        const size_t s = (size_t)l * DD * DD + k * DD + n;
        w1t[tid] = f2bf(W1[s]);
        w2t[tid] = f2bf(W2[s]);
    }
}

// ---------------- MFMA edge kernel ----------------
// EB=128 edges/block, 4 waves, 32 KB LDS -> 5 blocks/CU.
// Bias folded into Phase B (per-thread scalar add before bf16 store).
// Phase C (R10-proven): 2x16-edge batches, acc/seg carried across the window.
__global__ __launch_bounds__(256, 5) void edge_mfma_kernel(
    const unsigned short* __restrict__ xbf,   // [NN][DD] bf16
    const unsigned short* __restrict__ eab,   // [NE][ED] bf16, dst-sorted
    const int2* __restrict__ sd_perm,         // [NE+1] (src,dst), dst-sorted
    const unsigned short* __restrict__ wtb,   // [DD][ED] bf16 (layer slice)
    const float* __restrict__ be,
    float* __restrict__ agg)
{
    __shared__ unsigned short msgl[EB * 128];   // 32 KB
    const int t = threadIdx.x;
    const int wv = t >> 6, ln = t & 63;
    const int l15 = ln & 15, kb = ln >> 4;

    // XCD swizzle (nwg = NE/EB = 6250, bijective m204 form) — neutral but free
    const int nwg = NE / EB;
    const int q = nwg >> 3, r = nwg & 7;
    const int xcd = blockIdx.x & 7, seq = blockIdx.x >> 3;
    const int wg = (xcd < r ? xcd * (q + 1) : r * (q + 1) + (xcd - r) * q) + seq;
    const int e0 = wg * EB;

    const int c0 = (2 * wv + 0) * 16 + l15;
    const int c1 = (2 * wv + 1) * 16 + l15;
    const bf16x8 bfr0 = *(const bf16x8*)&wtb[c0 * ED + kb * 8];
    const bf16x8 bfr1 = *(const bf16x8*)&wtb[c1 * ED + kb * 8];
    const float bv0 = be[c0], bv1 = be[c1];   // per-thread scalars (cols fixed)

#pragma unroll
    for (int eg = 0; eg < EB / 16; ++eg) {
        const int edge = eg * 16 + l15;
        const bf16x8 afr = *(const bf16x8*)&eab[(size_t)(e0 + edge) * ED + kb * 8];
        f32x4 z = {0.f, 0.f, 0.f, 0.f};
        const f32x4 d0 = __builtin_amdgcn_mfma_f32_16x16x32_bf16(afr, bfr0, z, 0, 0, 0);
        const f32x4 d1 = __builtin_amdgcn_mfma_f32_16x16x32_bf16(afr, bfr1, z, 0, 0, 0);
#pragma unroll
        for (int j = 0; j < 4; ++j) {
            const int mrow = eg * 16 + kb * 4 + j;
            const int sw = ((mrow >> 2) & 3) << 3;
            const int i0 = (((c0 >> 1) ^ sw) << 1) | (c0 & 1);
            const int i1 = (((c1 >> 1) ^ sw) << 1) | (c1 & 1);
            msgl[mrow * 128 + i0] = f2bf(d0[j] + bv0);   // bias folded here
            msgl[mrow * 128 + i1] = f2bf(d1[j] + bv1);
        }
    }
    __syncthreads();

    // Phase C: segmented reduce, 32 sorted edges per wave (2 batches of 16,
    // acc and seg_start carried across the whole window).
    const int lbase = wv * 32;
    const int2* sdp = &sd_perm[e0 + lbase];
    const int c2 = ln * 2;
    float2 acc = {0.f, 0.f};
    int seg_start = 0;
#pragma unroll 1
    for (int g = 0; g < 2; ++g) {
        const int gb = g * 16;
        int4 pr[8];
#pragma unroll
        for (int q2 = 0; q2 < 8; ++q2)
            pr[q2] = *(const int4*)&sdp[gb + 2 * q2];
        int srcs[16], dsts[17];
#pragma unroll
        for (int q2 = 0; q2 < 8; ++q2) {
            srcs[2 * q2] = pr[q2].x; srcs[2 * q2 + 1] = pr[q2].z;
            dsts[2 * q2] = pr[q2].y; dsts[2 * q2 + 1] = pr[q2].w;
        }
        dsts[16] = sdp[gb + 16].y;    // sentinel-backed: valid at window end too
        float2 xv[16];
#pragma unroll
        for (int q2 = 0; q2 < 16; ++q2) {
            const unsigned xu = *(const unsigned*)&xbf[(size_t)srcs[q2] * DD + c2];
            xv[q2].x = __uint_as_float(xu << 16);
            xv[q2].y = __uint_as_float(xu & 0xffff0000u);
        }
#pragma unroll
        for (int q2 = 0; q2 < 16; ++q2) {
            const int i = gb + q2;
            const int dw = ln ^ (((i >> 2) & 3) << 3);
            const unsigned mm = *(const unsigned*)&msgl[(lbase + i) * 128 + dw * 2];
            const float mlo = __uint_as_float(mm << 16);
            const float mhi = __uint_as_float(mm & 0xffff0000u);
            acc.x += fmaxf(xv[q2].x + mlo, 0.f);
            acc.y += fmaxf(xv[q2].y + mhi, 0.f);
            if (i == 31 || dsts[q2 + 1] != dsts[q2]) {
                float* ap = &agg[(size_t)dsts[q2] * DD + c2];
                if (seg_start > 0 && i < 31) {
                    *(float2*)ap = acc;             // interior: sole writer
                } else {
                    unsafeAtomicAdd(ap + 0, acc.x); // chunk-boundary segment
                    unsafeAtomicAdd(ap + 1, acc.y);
                }
                acc.x = 0.f; acc.y = 0.f;
                seg_start = i + 1;
            }
        }
    }
}

// ---------------- MFMA node MLP kernel ----------------
// MR=32 rows/block, 4 waves (wave owns 32 output cols), 24 KB LDS, 5 blocks/CU.
// GEMM1: split bf16 (hi+lo) for h = x+agg. GEMM2: hi-only (h1 is relu'd, small).
__global__ __launch_bounds__(256, 5) void mlp_mfma_kernel(
    const unsigned short* __restrict__ xbf, const float* __restrict__ agg,
    float* __restrict__ h2out,
    const unsigned short* __restrict__ w1t,   // [DD][DD] bf16 [n][k] (layer slice)
    const unsigned short* __restrict__ w2t,
    const float* __restrict__ b1, const float* __restrict__ b2,
    float* __restrict__ bns)
{
    __shared__ unsigned short ah[MR * 128];  // 8 KB h hi
    __shared__ unsigned short al[MR * 128];  // 8 KB h lo
    __shared__ unsigned short bh[MR * 128];  // 8 KB h1
    const int t = threadIdx.x;
    const int wv = t >> 6, ln = t & 63, l15 = ln & 15, kb = ln >> 4;
    const int r0 = blockIdx.x * MR;

    // ---- stage h = x + agg -> split bf16, swizzled (2 passes x 16 rows x 16 granules) ----
#pragma unroll
    for (int p = 0; p < 2; ++p) {
        const int row = p * 16 + (t >> 4);
        const int gc = t & 15;
        const int grow = r0 + row;
        float v[8] = {0.f, 0.f, 0.f, 0.f, 0.f, 0.f, 0.f, 0.f};
        if (grow < NN) {
            const size_t g = (size_t)grow * DD + gc * 8;
            const uint4 xu = *(const uint4*)&xbf[g];
            const float4 ga = *(const float4*)&agg[g];
            const float4 gb4 = *(const float4*)&agg[g + 4];
            v[0] = __uint_as_float(xu.x << 16)          + ga.x;
            v[1] = __uint_as_float(xu.x & 0xffff0000u)  + ga.y;
            v[2] = __uint_as_float(xu.y << 16)          + ga.z;
            v[3] = __uint_as_float(xu.y & 0xffff0000u)  + ga.w;
            v[4] = __uint_as_float(xu.z << 16)          + gb4.x;
            v[5] = __uint_as_float(xu.z & 0xffff0000u)  + gb4.y;
            v[6] = __uint_as_float(xu.w << 16)          + gb4.z;
            v[7] = __uint_as_float(xu.w & 0xffff0000u)  + gb4.w;
        }
        unsigned hiw[4], low[4];
#pragma unroll
        for (int j = 0; j < 4; ++j) {
            const unsigned short h0 = f2bf(v[2 * j]);
            const unsigned short h1 = f2bf(v[2 * j + 1]);
            const unsigned short q0 = f2bf(v[2 * j] - bf2f(h0));
            const unsigned short q1 = f2bf(v[2 * j + 1] - bf2f(h1));
            hiw[j] = (unsigned)h0 | ((unsigned)h1 << 16);
            low[j] = (unsigned)q0 | ((unsigned)q1 << 16);
        }
        const int off = row * 128 + (gc ^ (row & 7)) * 8;
        *(uint4*)&ah[off] = *(uint4*)hiw;
        *(uint4*)&al[off] = *(uint4*)low;
    }

    // B fragments for GEMM1
    bf16x8 w1f[2][4];
#pragma unroll
    for (int nt = 0; nt < 2; ++nt) {
        const int n = wv * 32 + nt * 16 + l15;
#pragma unroll
        for (int ks = 0; ks < 4; ++ks)
            w1f[nt][ks] = *(const bf16x8*)&w1t[n * DD + ks * 32 + kb * 8];
    }
    const int cA = wv * 32 + l15, cB = wv * 32 + 16 + l15;
    const float b1v[2] = {b1[cA], b1[cB]};
    const float b2v[2] = {b2[cA], b2[cB]};
    __syncthreads();

    // ---- GEMM1 (split hi+lo) ----
    f32x4 acc[2][2];
#pragma unroll
    for (int mt = 0; mt < 2; ++mt)
#pragma unroll
        for (int nt = 0; nt < 2; ++nt)
            acc[mt][nt] = (f32x4){0.f, 0.f, 0.f, 0.f};
#pragma unroll
    for (int ks = 0; ks < 4; ++ks) {
#pragma unroll
        for (int mt = 0; mt < 2; ++mt) {
            const int row = mt * 16 + l15;
            const int off = row * 128 + ((ks * 4 + kb) ^ (row & 7)) * 8;
            const bf16x8 afh = *(const bf16x8*)&ah[off];
            const bf16x8 afl = *(const bf16x8*)&al[off];
#pragma unroll
            for (int nt = 0; nt < 2; ++nt) {
                acc[mt][nt] = __builtin_amdgcn_mfma_f32_16x16x32_bf16(afh, w1f[nt][ks], acc[mt][nt], 0, 0, 0);
                acc[mt][nt] = __builtin_amdgcn_mfma_f32_16x16x32_bf16(afl, w1f[nt][ks], acc[mt][nt], 0, 0, 0);
            }
        }
    }

    // ---- h1 = relu(acc + b1) -> bf16 LDS (hi only) ----
#pragma unroll
    for (int mt = 0; mt < 2; ++mt) {
#pragma unroll
        for (int nt = 0; nt < 2; ++nt) {
            const int col = wv * 32 + nt * 16 + l15;
#pragma unroll
            for (int j = 0; j < 4; ++j) {
                const int row = mt * 16 + kb * 4 + j;
                const float v = fmaxf(acc[mt][nt][j] + b1v[nt], 0.f);
                const int off = row * 128 + ((col >> 3) ^ (row & 7)) * 8 + (col & 7);
                bh[off] = f2bf(v);
            }
        }
    }

    // B fragments for GEMM2
    bf16x8 w2f[2][4];
#pragma unroll
    for (int nt = 0; nt < 2; ++nt) {
        const int n = wv * 32 + nt * 16 + l15;
#pragma unroll
        for (int ks = 0; ks < 4; ++ks)
            w2f[nt][ks] = *(const bf16x8*)&w2t[n * DD + ks * 32 + kb * 8];
    }
    __syncthreads();

    // ---- GEMM2 (hi only) ----
#pragma unroll
    for (int mt = 0; mt < 2; ++mt)
#pragma unroll
        for (int nt = 0; nt < 2; ++nt)
            acc[mt][nt] = (f32x4){0.f, 0.f, 0.f, 0.f};
#pragma unroll
    for (int ks = 0; ks < 4; ++ks) {
#pragma unroll
        for (int mt = 0; mt < 2; ++mt) {
            const int row = mt * 16 + l15;
            const int off = row * 128 + ((ks * 4 + kb) ^ (row & 7)) * 8;
            const bf16x8 afh = *(const bf16x8*)&bh[off];
#pragma unroll
            for (int nt = 0; nt < 2; ++nt)
                acc[mt][nt] = __builtin_amdgcn_mfma_f32_16x16x32_bf16(afh, w2f[nt][ks], acc[mt][nt], 0, 0, 0);
        }
    }

    // ---- epilogue: h2 store + BN partial sums ----
    float ps[2] = {0.f, 0.f}, pq[2] = {0.f, 0.f};
#pragma unroll
    for (int mt = 0; mt < 2; ++mt) {
#pragma unroll
        for (int nt = 0; nt < 2; ++nt) {
            const int col = wv * 32 + nt * 16 + l15;
#pragma unroll
            for (int j = 0; j < 4; ++j) {
                const int row = r0 + mt * 16 + kb * 4 + j;
                const float v = acc[mt][nt][j] + b2v[nt];
                if (row < NN) {
                    h2out[(size_t)row * DD + col] = v;
                    ps[nt] += v;
                    pq[nt] += v * v;
                }
            }
        }
    }
#pragma unroll
    for (int nt = 0; nt < 2; ++nt) {
        ps[nt] += __shfl_xor(ps[nt], 16);
        ps[nt] += __shfl_xor(ps[nt], 32);
        pq[nt] += __shfl_xor(pq[nt], 16);
        pq[nt] += __shfl_xor(pq[nt], 32);
    }
    if (kb == 0) {
#pragma unroll
        for (int nt = 0; nt < 2; ++nt) {
            const int col = wv * 32 + nt * 16 + l15;
            unsafeAtomicAdd(&bns[col], ps[nt]);
            unsafeAtomicAdd(&bns[DD + col], pq[nt]);
        }
    }
}

// ---------------- BN apply + ReLU -> bf16 x; also zeroes agg for next layer ----------------
__global__ __launch_bounds__(256) void bn_apply_bf16(
    float* __restrict__ h2, const float* __restrict__ bns,
    const float* __restrict__ gamma, const float* __restrict__ beta,
    unsigned short* __restrict__ xout)
{
    const size_t i = ((size_t)blockIdx.x * 256 + threadIdx.x) * 4;
    if (i >= (size_t)NN * DD) return;
    const int c4 = (int)(i & 127);
    const float4 hv = *(const float4*)&h2[i];
    const float4 sv = *(const float4*)&bns[c4];
    const float4 qv = *(const float4*)&bns[DD + c4];
    const float4 gv = *(const float4*)&gamma[c4];
    const float4 bv = *(const float4*)&beta[c4];
    const float inv_n = 1.f / (float)NN;
    float o0, o1, o2, o3;
    { const float m = sv.x * inv_n; const float var = qv.x * inv_n - m * m;
      o0 = fmaxf((hv.x - m) * __frsqrt_rn(var + BN_EPS) * gv.x + bv.x, 0.f); }
    { const float m = sv.y * inv_n; const float var = qv.y * inv_n - m * m;
      o1 = fmaxf((hv.y - m) * __frsqrt_rn(var + BN_EPS) * gv.y + bv.y, 0.f); }
    { const float m = sv.z * inv_n; const float var = qv.z * inv_n - m * m;
      o2 = fmaxf((hv.z - m) * __frsqrt_rn(var + BN_EPS) * gv.z + bv.z, 0.f); }
    { const float m = sv.w * inv_n; const float var = qv.w * inv_n - m * m;
      o3 = fmaxf((hv.w - m) * __frsqrt_rn(var + BN_EPS) * gv.w + bv.w, 0.f); }
    uint2 o;
    o.x = (unsigned)f2bf(o0) | ((unsigned)f2bf(o1) << 16);
    o.y = (unsigned)f2bf(o2) | ((unsigned)f2bf(o3) << 16);
    *(uint2*)&xout[i] = o;
    *(float4*)&h2[i] = (float4){0.f, 0.f, 0.f, 0.f};   // fused agg zeroing
}

// ---------------- BN apply + ReLU -> f32 out (final layer) ----------------
__global__ __launch_bounds__(256) void bn_apply_f32(
    const float* __restrict__ h2, const float* __restrict__ bns,
    const float* __restrict__ gamma, const float* __restrict__ beta,
    float* __restrict__ xout)
{
    const size_t i = ((size_t)blockIdx.x * 256 + threadIdx.x) * 4;
    if (i >= (size_t)NN * DD) return;
    const int c4 = (int)(i & 127);
    const float4 hv = *(const float4*)&h2[i];
    const float4 sv = *(const float4*)&bns[c4];
    const float4 qv = *(const float4*)&bns[DD + c4];
    const float4 gv = *(const float4*)&gamma[c4];
    const float4 bv = *(const float4*)&beta[c4];
    const float inv_n = 1.f / (float)NN;
    float4 ov;
    { const float m = sv.x * inv_n; const float var = qv.x * inv_n - m * m;
      ov.x = fmaxf((hv.x - m) * __frsqrt_rn(var + BN_EPS) * gv.x + bv.x, 0.f); }
    { const float m = sv.y * inv_n; const float var = qv.y * inv_n - m * m;
      ov.y = fmaxf((hv.y - m) * __frsqrt_rn(var + BN_EPS) * gv.y + bv.y, 0.f); }
    { const float m = sv.z * inv_n; const float var = qv.z * inv_n - m * m;
      ov.z = fmaxf((hv.z - m) * __frsqrt_rn(var + BN_EPS) * gv.z + bv.z, 0.f); }
    { const float m = sv.w * inv_n; const float var = qv.w * inv_n - m * m;
      ov.w = fmaxf((hv.w - m) * __frsqrt_rn(var + BN_EPS) * gv.w + bv.w, 0.f); }
    *(float4*)&xout[i] = ov;
}

extern "C" void kernel_launch(void* const* d_in, const int* in_sizes, int n_in,
                              void* d_out, int out_size, void* d_ws, size_t ws_size,
                              hipStream_t stream) {
    const float* x0    = (const float*)d_in[0];
    const float* ea    = (const float*)d_in[1];
    const int*   eidx  = (const int*)d_in[2];
    const float* We    = (const float*)d_in[3];
    const float* be    = (const float*)d_in[4];
    const float* W1    = (const float*)d_in[5];
    const float* b1    = (const float*)d_in[6];
    const float* W2    = (const float*)d_in[7];
    const float* b2    = (const float*)d_in[8];
    const float* gamma = (const float*)d_in[9];
    const float* beta  = (const float*)d_in[10];
    float* out = (float*)d_out;
    float* ws  = (float*)d_ws;

    float* agg = ws;                              // NN*DD f32 (doubles as h2)
    float* bns = agg + (size_t)NN * DD;           // NL*256
    int* deg      = (int*)(bns + NL * 256);       // 50000
    int* rowptr   = deg + 50000;                  // 50004 (padded)
    int* cursor   = rowptr + 50004;               // 50000
    int* bsum     = cursor + 50000;               // 64
    int2* sd_perm = (int2*)(bsum + 64);           // NE+1 int2 (sentinel)
    int* eid_perm = (int*)(sd_perm + NE + 2);     // NE
    unsigned short* ea_bf = (unsigned short*)(eid_perm + NE);  // NE*ED
    unsigned short* wt_bf = ea_bf + (size_t)NE * ED;           // NL*DD*ED
    unsigned short* w1t   = wt_bf + (size_t)NL * DD * ED;      // NL*DD*DD
    unsigned short* w2t   = w1t + (size_t)NL * DD * DD;        // NL*DD*DD
    unsigned short* xbf   = w2t + (size_t)NL * DD * DD;        // NN*DD bf16

    const int* esrc = eidx;
    const int* edst = eidx + NE;

    // ---- CSR build + bf16 pre-conversion (once; reused by all 4 layers) ----
    hipMemsetAsync(deg, 0, NN * sizeof(int), stream);
    hipMemsetAsync(bns, 0, NL * 256 * sizeof(float), stream);
    hipMemsetAsync(agg, 0, (size_t)NN * DD * sizeof(float), stream);
    hist_kernel<<<(NE + 255) / 256, 256, 0, stream>>>(edst, deg);
    scan1_kernel<<<NB, 256, 0, stream>>>(deg, rowptr, bsum);
    scan2_kernel<<<1, 64, 0, stream>>>(bsum);
    scan3_kernel<<<(NN + 255) / 256, 256, 0, stream>>>(rowptr, cursor, bsum);
    scatter_idx_kernel<<<(NE + 255) / 256, 256, 0, stream>>>(edst, cursor, eid_perm);
    sdea_kernel<<<((size_t)NE * 8 + 255) / 256, 256, 0, stream>>>(
        eid_perm, esrc, edst, ea, sd_perm, ea_bf);
    x0conv_kernel<<<((NN * DD / 8) + 255) / 256, 256, 0, stream>>>(x0, xbf);
    wconv_kernel<<<(NL * DD * ED + 255) / 256, 256, 0, stream>>>(We, wt_bf);
    w12conv_kernel<<<(NL * DD * DD + 255) / 256, 256, 0, stream>>>(W1, W2, w1t, w2t);

    for (int l = 0; l < NL; ++l) {
        edge_mfma_kernel<<<NE / EB, 256, 0, stream>>>(
            xbf, ea_bf, sd_perm,
            wt_bf + (size_t)l * DD * ED, be + (size_t)l * DD, agg);
        mlp_mfma_kernel<<<(NN + MR - 1) / MR, 256, 0, stream>>>(
            xbf, agg, agg,
            w1t + (size_t)l * DD * DD, w2t + (size_t)l * DD * DD,
            b1 + (size_t)l * DD, b2 + (size_t)l * DD, bns + l * 256);
        if (l < NL - 1) {
            bn_apply_bf16<<<(NN * DD / 4 + 255) / 256, 256, 0, stream>>>(
                agg, bns + l * 256, gamma + (size_t)l * DD, beta + (size_t)l * DD, xbf);
        } else {
            bn_apply_f32<<<(NN * DD / 4 + 255) / 256, 256, 0, stream>>>(
                agg, bns + l * 256, gamma + (size_t)l * DD, beta + (size_t)l * DD, out);
        }
    }
}

// Round 14
// 610.905 us; speedup vs baseline: 1.3642x; 1.0728x over previous
//
#include <hip/hip_runtime.h>

#define NN 50000
#define NE 800000
#define DD 128
#define ED 32
#define NL 4
#define BN_EPS 1e-5f
#define SCAN_B 1024
#define NB ((NN + SCAN_B - 1) / SCAN_B)   // 49
#define EB 128                            // edges per block (edge kernel)
#define MR 32                             // rows per block (mlp kernel)

typedef __attribute__((ext_vector_type(8))) short bf16x8;
typedef __attribute__((ext_vector_type(4))) float f32x4;

__device__ __forceinline__ unsigned short f2bf(float f) {
    unsigned u = __float_as_uint(f);
    u += 0x7fffu + ((u >> 16) & 1u);
    return (unsigned short)(u >> 16);
}
__device__ __forceinline__ float bf2f(unsigned short h) {
    return __uint_as_float((unsigned)h << 16);
}

// ---------------- CSR build ----------------
// hist + rank in one pass: rank[e] = arrival index within dst bucket
__global__ __launch_bounds__(256) void hist_rank_kernel(
    const int* __restrict__ edst, int* __restrict__ deg, int* __restrict__ rank)
{
    const int e = blockIdx.x * 256 + threadIdx.x;
    if (e < NE) rank[e] = atomicAdd(&deg[edst[e]], 1);
}

__global__ __launch_bounds__(256) void scan1_kernel(
    const int* __restrict__ deg, int* __restrict__ rowptr, int* __restrict__ bsum)
{
    __shared__ int sh[256];
    const int t = threadIdx.x, b = blockIdx.x;
    const int base = b * SCAN_B + t * 4;
    int v[4];
#pragma unroll
    for (int j = 0; j < 4; ++j) {
        const int idx = base + j;
        v[j] = (idx < NN) ? deg[idx] : 0;
    }
    sh[t] = v[0] + v[1] + v[2] + v[3];
    __syncthreads();
    for (int off = 1; off < 256; off <<= 1) {
        const int val = (t >= off) ? sh[t - off] : 0;
        __syncthreads();
        sh[t] += val;
        __syncthreads();
    }
    int p = (t == 0) ? 0 : sh[t - 1];
#pragma unroll
    for (int j = 0; j < 4; ++j) {
        const int idx = base + j;
        if (idx < NN) rowptr[idx] = p;
        p += v[j];
    }
    if (t == 255) bsum[b] = sh[255];
}

__global__ void scan2_kernel(int* __restrict__ bsum)
{
    if (threadIdx.x == 0) {
        int acc = 0;
        for (int i = 0; i < NB; ++i) { const int v = bsum[i]; bsum[i] = acc; acc += v; }
    }
}

__global__ __launch_bounds__(256) void scan3_kernel(
    int* __restrict__ rowptr, const int* __restrict__ bsum)
{
    const int idx = blockIdx.x * 256 + threadIdx.x;
    if (idx < NN) rowptr[idx] += bsum[idx / SCAN_B];
    if (idx == 0) rowptr[NN] = NE;
}

// place: pos = rowptr[dst] + rank  (no atomics; scattered 4B write)
__global__ __launch_bounds__(256) void place_kernel(
    const int* __restrict__ edst, const int* __restrict__ rowptr,
    const int* __restrict__ rank, int* __restrict__ eid_perm)
{
    const int e = blockIdx.x * 256 + threadIdx.x;
    if (e < NE) eid_perm[rowptr[edst[e]] + rank[e]] = e;
}

// per sorted position (8 lanes/edge): fill packed (src|dst<<16) + gather ea row -> bf16.
__global__ __launch_bounds__(256) void sdea_kernel(
    const int* __restrict__ eid_perm, const int* __restrict__ esrc,
    const int* __restrict__ edst, const float* __restrict__ ea,
    unsigned* __restrict__ sd_pk, unsigned short* __restrict__ ea_bf)
{
    const int tid = blockIdx.x * 256 + threadIdx.x;
    const int pos = tid >> 3, j = tid & 7;
    if (pos < NE) {
        const int e = eid_perm[pos];
        if (j == 0)
            sd_pk[pos] = (unsigned)esrc[e] | ((unsigned)edst[e] << 16);
        const float4 v = *(const float4*)&ea[(size_t)e * ED + j * 4];
        uint2 p;
        p.x = (unsigned)f2bf(v.x) | ((unsigned)f2bf(v.y) << 16);
        p.y = (unsigned)f2bf(v.z) | ((unsigned)f2bf(v.w) << 16);
        *(uint2*)&ea_bf[(size_t)pos * ED + j * 4] = p;
    }
    if (tid == 0) sd_pk[NE] = 0xFFFF0000u;   // sentinel dst=0xFFFF (> any node id)
}

// x0 f32 -> bf16 (once per call, feeds layer 0)
__global__ __launch_bounds__(256) void x0conv_kernel(
    const float* __restrict__ x0, unsigned short* __restrict__ xbf)
{
    const size_t i = ((size_t)blockIdx.x * 256 + threadIdx.x) * 8;
    if (i >= (size_t)NN * DD) return;
    const float4 a = *(const float4*)&x0[i];
    const float4 b = *(const float4*)&x0[i + 4];
    uint4 o;
    o.x = (unsigned)f2bf(a.x) | ((unsigned)f2bf(a.y) << 16);
    o.y = (unsigned)f2bf(a.z) | ((unsigned)f2bf(a.w) << 16);
    o.z = (unsigned)f2bf(b.x) | ((unsigned)f2bf(b.y) << 16);
    o.w = (unsigned)f2bf(b.z) | ((unsigned)f2bf(b.w) << 16);
    *(uint4*)&xbf[i] = o;
}

// W_edge [NL][ED][DD] f32 -> wtb bf16 [NL][DD][ED] (transposed, contiguous in K)
__global__ __launch_bounds__(256) void wconv_kernel(
    const float* __restrict__ We, unsigned short* __restrict__ wtb)
{
    const int tid = blockIdx.x * 256 + threadIdx.x;
    if (tid < NL * DD * ED) {
        const int l = tid / (DD * ED);
        const int r = tid % (DD * ED);
        const int c = r / ED, k = r % ED;
        wtb[tid] = f2bf(We[(size_t)l * ED * DD + k * DD + c]);
    }
}

// W1/W2 [NL][DD][DD] f32 ([k][n]) -> bf16 [NL][DD][DD] ([n][k])
__global__ __launch_bounds__(256) void w12conv_kernel(
    const float* __restrict__ W1, const float* __restrict__ W2,
    unsigned short* __restrict__ w1t, unsigned short* __restrict__ w2t)
{
    const int tid = blockIdx.x * 256 + threadIdx.x;
    if (tid < NL * DD * DD) {
        const int l = tid / (DD * DD);
        const int r = tid % (DD * DD);
        const int n = r / DD, k = r % DD;
        const size_t s = (size_t)l * DD * DD + k * DD + n;
        w1t[tid] = f2bf(W1[s]);
        w2t[tid] = f2bf(W2[s]);
    }
}

// ---------------- MFMA edge kernel ----------------
// EB=128 edges/block, 4 waves, 32 KB LDS -> 5 blocks/CU.
// Bias folded into Phase B. Phase C: 2x16-edge batches (R10-proven working set),
// packed u32 (src|dst<<16) indices — half the index bytes and loads.
__global__ __launch_bounds__(256, 5) void edge_mfma_kernel(
    const unsigned short* __restrict__ xbf,   // [NN][DD] bf16
    const unsigned short* __restrict__ eab,   // [NE][ED] bf16, dst-sorted
    const unsigned* __restrict__ sd_pk,       // [NE+1] packed (src|dst<<16)
    const unsigned short* __restrict__ wtb,   // [DD][ED] bf16 (layer slice)
    const float* __restrict__ be,
    float* __restrict__ agg)
{
    __shared__ unsigned short msgl[EB * 128];   // 32 KB
    const int t = threadIdx.x;
    const int wv = t >> 6, ln = t & 63;
    const int l15 = ln & 15, kb = ln >> 4;

    // XCD swizzle (nwg = NE/EB = 6250, bijective m204 form) — neutral but free
    const int nwg = NE / EB;
    const int q = nwg >> 3, r = nwg & 7;
    const int xcd = blockIdx.x & 7, seq = blockIdx.x >> 3;
    const int wg = (xcd < r ? xcd * (q + 1) : r * (q + 1) + (xcd - r) * q) + seq;
    const int e0 = wg * EB;

    const int c0 = (2 * wv + 0) * 16 + l15;
    const int c1 = (2 * wv + 1) * 16 + l15;
    const bf16x8 bfr0 = *(const bf16x8*)&wtb[c0 * ED + kb * 8];
    const bf16x8 bfr1 = *(const bf16x8*)&wtb[c1 * ED + kb * 8];
    const float bv0 = be[c0], bv1 = be[c1];

#pragma unroll
    for (int eg = 0; eg < EB / 16; ++eg) {
        const int edge = eg * 16 + l15;
        const bf16x8 afr = *(const bf16x8*)&eab[(size_t)(e0 + edge) * ED + kb * 8];
        f32x4 z = {0.f, 0.f, 0.f, 0.f};
        const f32x4 d0 = __builtin_amdgcn_mfma_f32_16x16x32_bf16(afr, bfr0, z, 0, 0, 0);
        const f32x4 d1 = __builtin_amdgcn_mfma_f32_16x16x32_bf16(afr, bfr1, z, 0, 0, 0);
#pragma unroll
        for (int j = 0; j < 4; ++j) {
            const int mrow = eg * 16 + kb * 4 + j;
            const int sw = ((mrow >> 2) & 3) << 3;
            const int i0 = (((c0 >> 1) ^ sw) << 1) | (c0 & 1);
            const int i1 = (((c1 >> 1) ^ sw) << 1) | (c1 & 1);
            msgl[mrow * 128 + i0] = f2bf(d0[j] + bv0);   // bias folded here
            msgl[mrow * 128 + i1] = f2bf(d1[j] + bv1);
        }
    }
    __syncthreads();

    // Phase C: segmented reduce, 32 sorted edges per wave (2 batches of 16,
    // acc and seg_start carried across the whole window).
    const int lbase = wv * 32;
    const unsigned* sdp = &sd_pk[e0 + lbase];
    const int c2 = ln * 2;
    float2 acc = {0.f, 0.f};
    int seg_start = 0;
#pragma unroll 1
    for (int g = 0; g < 2; ++g) {
        const int gb = g * 16;
        uint4 pr[4];
#pragma unroll
        for (int q2 = 0; q2 < 4; ++q2)
            pr[q2] = *(const uint4*)&sdp[gb + 4 * q2];
        unsigned pk[17];
#pragma unroll
        for (int q2 = 0; q2 < 4; ++q2) {
            pk[4 * q2 + 0] = pr[q2].x; pk[4 * q2 + 1] = pr[q2].y;
            pk[4 * q2 + 2] = pr[q2].z; pk[4 * q2 + 3] = pr[q2].w;
        }
        pk[16] = sdp[gb + 16];        // sentinel-backed: valid at window end too
        float2 xv[16];
#pragma unroll
        for (int q2 = 0; q2 < 16; ++q2) {
            const unsigned src = pk[q2] & 0xFFFFu;
            const unsigned xu = *(const unsigned*)&xbf[(size_t)src * DD + c2];
            xv[q2].x = __uint_as_float(xu << 16);
            xv[q2].y = __uint_as_float(xu & 0xffff0000u);
        }
#pragma unroll
        for (int q2 = 0; q2 < 16; ++q2) {
            const int i = gb + q2;
            const int dw = ln ^ (((i >> 2) & 3) << 3);
            const unsigned mm = *(const unsigned*)&msgl[(lbase + i) * 128 + dw * 2];
            const float mlo = __uint_as_float(mm << 16);
            const float mhi = __uint_as_float(mm & 0xffff0000u);
            acc.x += fmaxf(xv[q2].x + mlo, 0.f);
            acc.y += fmaxf(xv[q2].y + mhi, 0.f);
            const unsigned d_cur = pk[q2] >> 16;
            if (i == 31 || (pk[q2 + 1] >> 16) != d_cur) {
                float* ap = &agg[(size_t)d_cur * DD + c2];
                if (seg_start > 0 && i < 31) {
                    *(float2*)ap = acc;             // interior: sole writer
                } else {
                    unsafeAtomicAdd(ap + 0, acc.x); // chunk-boundary segment
                    unsafeAtomicAdd(ap + 1, acc.y);
                }
                acc.x = 0.f; acc.y = 0.f;
                seg_start = i + 1;
            }
        }
    }
}

// ---------------- MFMA node MLP kernel ----------------
// MR=32 rows/block, 4 waves (wave owns 32 output cols), 24 KB LDS, 5 blocks/CU.
// GEMM1: split bf16 (hi+lo) for h = x+agg. GEMM2: hi-only (h1 is relu'd, small).
__global__ __launch_bounds__(256, 5) void mlp_mfma_kernel(
    const unsigned short* __restrict__ xbf, const float* __restrict__ agg,
    float* __restrict__ h2out,
    const unsigned short* __restrict__ w1t,   // [DD][DD] bf16 [n][k] (layer slice)
    const unsigned short* __restrict__ w2t,
    const float* __restrict__ b1, const float* __restrict__ b2,
    float* __restrict__ bns)
{
    __shared__ unsigned short ah[MR * 128];  // 8 KB h hi
    __shared__ unsigned short al[MR * 128];  // 8 KB h lo
    __shared__ unsigned short bh[MR * 128];  // 8 KB h1
    const int t = threadIdx.x;
    const int wv = t >> 6, ln = t & 63, l15 = ln & 15, kb = ln >> 4;
    const int r0 = blockIdx.x * MR;

    // ---- stage h = x + agg -> split bf16, swizzled (2 passes x 16 rows x 16 granules) ----
#pragma unroll
    for (int p = 0; p < 2; ++p) {
        const int row = p * 16 + (t >> 4);
        const int gc = t & 15;
        const int grow = r0 + row;
        float v[8] = {0.f, 0.f, 0.f, 0.f, 0.f, 0.f, 0.f, 0.f};
        if (grow < NN) {
            const size_t g = (size_t)grow * DD + gc * 8;
            const uint4 xu = *(const uint4*)&xbf[g];
            const float4 ga = *(const float4*)&agg[g];
            const float4 gb4 = *(const float4*)&agg[g + 4];
            v[0] = __uint_as_float(xu.x << 16)          + ga.x;
            v[1] = __uint_as_float(xu.x & 0xffff0000u)  + ga.y;
            v[2] = __uint_as_float(xu.y << 16)          + ga.z;
            v[3] = __uint_as_float(xu.y & 0xffff0000u)  + ga.w;
            v[4] = __uint_as_float(xu.z << 16)          + gb4.x;
            v[5] = __uint_as_float(xu.z & 0xffff0000u)  + gb4.y;
            v[6] = __uint_as_float(xu.w << 16)          + gb4.z;
            v[7] = __uint_as_float(xu.w & 0xffff0000u)  + gb4.w;
        }
        unsigned hiw[4], low[4];
#pragma unroll
        for (int j = 0; j < 4; ++j) {
            const unsigned short h0 = f2bf(v[2 * j]);
            const unsigned short h1 = f2bf(v[2 * j + 1]);
            const unsigned short q0 = f2bf(v[2 * j] - bf2f(h0));
            const unsigned short q1 = f2bf(v[2 * j + 1] - bf2f(h1));
            hiw[j] = (unsigned)h0 | ((unsigned)h1 << 16);
            low[j] = (unsigned)q0 | ((unsigned)q1 << 16);
        }
        const int off = row * 128 + (gc ^ (row & 7)) * 8;
        *(uint4*)&ah[off] = *(uint4*)hiw;
        *(uint4*)&al[off] = *(uint4*)low;
    }

    // B fragments for GEMM1
    bf16x8 w1f[2][4];
#pragma unroll
    for (int nt = 0; nt < 2; ++nt) {
        const int n = wv * 32 + nt * 16 + l15;
#pragma unroll
        for (int ks = 0; ks < 4; ++ks)
            w1f[nt][ks] = *(const bf16x8*)&w1t[n * DD + ks * 32 + kb * 8];
    }
    const int cA = wv * 32 + l15, cB = wv * 32 + 16 + l15;
    const float b1v[2] = {b1[cA], b1[cB]};
    const float b2v[2] = {b2[cA], b2[cB]};
    __syncthreads();

    // ---- GEMM1 (split hi+lo) ----
    f32x4 acc[2][2];
#pragma unroll
    for (int mt = 0; mt < 2; ++mt)
#pragma unroll
        for (int nt = 0; nt < 2; ++nt)
            acc[mt][nt] = (f32x4){0.f, 0.f, 0.f, 0.f};
#pragma unroll
    for (int ks = 0; ks < 4; ++ks) {
#pragma unroll
        for (int mt = 0; mt < 2; ++mt) {
            const int row = mt * 16 + l15;
            const int off = row * 128 + ((ks * 4 + kb) ^ (row & 7)) * 8;
            const bf16x8 afh = *(const bf16x8*)&ah[off];
            const bf16x8 afl = *(const bf16x8*)&al[off];
#pragma unroll
            for (int nt = 0; nt < 2; ++nt) {
                acc[mt][nt] = __builtin_amdgcn_mfma_f32_16x16x32_bf16(afh, w1f[nt][ks], acc[mt][nt], 0, 0, 0);
                acc[mt][nt] = __builtin_amdgcn_mfma_f32_16x16x32_bf16(afl, w1f[nt][ks], acc[mt][nt], 0, 0, 0);
            }
        }
    }

    // ---- h1 = relu(acc + b1) -> bf16 LDS (hi only) ----
#pragma unroll
    for (int mt = 0; mt < 2; ++mt) {
#pragma unroll
        for (int nt = 0; nt < 2; ++nt) {
            const int col = wv * 32 + nt * 16 + l15;
#pragma unroll
            for (int j = 0; j < 4; ++j) {
                const int row = mt * 16 + kb * 4 + j;
                const float v = fmaxf(acc[mt][nt][j] + b1v[nt], 0.f);
                const int off = row * 128 + ((col >> 3) ^ (row & 7)) * 8 + (col & 7);
                bh[off] = f2bf(v);
            }
        }
    }

    // B fragments for GEMM2
    bf16x8 w2f[2][4];
#pragma unroll
    for (int nt = 0; nt < 2; ++nt) {
        const int n = wv * 32 + nt * 16 + l15;
#pragma unroll
        for (int ks = 0; ks < 4; ++ks)
            w2f[nt][ks] = *(const bf16x8*)&w2t[n * DD + ks * 32 + kb * 8];
    }
    __syncthreads();

    // ---- GEMM2 (hi only) ----
#pragma unroll
    for (int mt = 0; mt < 2; ++mt)
#pragma unroll
        for (int nt = 0; nt < 2; ++nt)
            acc[mt][nt] = (f32x4){0.f, 0.f, 0.f, 0.f};
#pragma unroll
    for (int ks = 0; ks < 4; ++ks) {
#pragma unroll
        for (int mt = 0; mt < 2; ++mt) {
            const int row = mt * 16 + l15;
            const int off = row * 128 + ((ks * 4 + kb) ^ (row & 7)) * 8;
            const bf16x8 afh = *(const bf16x8*)&bh[off];
#pragma unroll
            for (int nt = 0; nt < 2; ++nt)
                acc[mt][nt] = __builtin_amdgcn_mfma_f32_16x16x32_bf16(afh, w2f[nt][ks], acc[mt][nt], 0, 0, 0);
        }
    }

    // ---- epilogue: h2 store + BN partial sums ----
    float ps[2] = {0.f, 0.f}, pq[2] = {0.f, 0.f};
#pragma unroll
    for (int mt = 0; mt < 2; ++mt) {
#pragma unroll
        for (int nt = 0; nt < 2; ++nt) {
            const int col = wv * 32 + nt * 16 + l15;
#pragma unroll
            for (int j = 0; j < 4; ++j) {
                const int row = r0 + mt * 16 + kb * 4 + j;
                const float v = acc[mt][nt][j] + b2v[nt];
                if (row < NN) {
                    h2out[(size_t)row * DD + col] = v;
                    ps[nt] += v;
                    pq[nt] += v * v;
                }
            }
        }
    }
#pragma unroll
    for (int nt = 0; nt < 2; ++nt) {
        ps[nt] += __shfl_xor(ps[nt], 16);
        ps[nt] += __shfl_xor(ps[nt], 32);
        pq[nt] += __shfl_xor(pq[nt], 16);
        pq[nt] += __shfl_xor(pq[nt], 32);
    }
    if (kb == 0) {
#pragma unroll
        for (int nt = 0; nt < 2; ++nt) {
            const int col = wv * 32 + nt * 16 + l15;
            unsafeAtomicAdd(&bns[col], ps[nt]);
            unsafeAtomicAdd(&bns[DD + col], pq[nt]);
        }
    }
}

// ---------------- BN apply + ReLU -> bf16 x; also zeroes agg for next layer ----------------
__global__ __launch_bounds__(256) void bn_apply_bf16(
    float* __restrict__ h2, const float* __restrict__ bns,
    const float* __restrict__ gamma, const float* __restrict__ beta,
    unsigned short* __restrict__ xout)
{
    const size_t i = ((size_t)blockIdx.x * 256 + threadIdx.x) * 4;
    if (i >= (size_t)NN * DD) return;
    const int c4 = (int)(i & 127);
    const float4 hv = *(const float4*)&h2[i];
    const float4 sv = *(const float4*)&bns[c4];
    const float4 qv = *(const float4*)&bns[DD + c4];
    const float4 gv = *(const float4*)&gamma[c4];
    const float4 bv = *(const float4*)&beta[c4];
    const float inv_n = 1.f / (float)NN;
    float o0, o1, o2, o3;
    { const float m = sv.x * inv_n; const float var = qv.x * inv_n - m * m;
      o0 = fmaxf((hv.x - m) * __frsqrt_rn(var + BN_EPS) * gv.x + bv.x, 0.f); }
    { const float m = sv.y * inv_n; const float var = qv.y * inv_n - m * m;
      o1 = fmaxf((hv.y - m) * __frsqrt_rn(var + BN_EPS) * gv.y + bv.y, 0.f); }
    { const float m = sv.z * inv_n; const float var = qv.z * inv_n - m * m;
      o2 = fmaxf((hv.z - m) * __frsqrt_rn(var + BN_EPS) * gv.z + bv.z, 0.f); }
    { const float m = sv.w * inv_n; const float var = qv.w * inv_n - m * m;
      o3 = fmaxf((hv.w - m) * __frsqrt_rn(var + BN_EPS) * gv.w + bv.w, 0.f); }
    uint2 o;
    o.x = (unsigned)f2bf(o0) | ((unsigned)f2bf(o1) << 16);
    o.y = (unsigned)f2bf(o2) | ((unsigned)f2bf(o3) << 16);
    *(uint2*)&xout[i] = o;
    *(float4*)&h2[i] = (float4){0.f, 0.f, 0.f, 0.f};   // fused agg zeroing
}

// ---------------- BN apply + ReLU -> f32 out (final layer) ----------------
__global__ __launch_bounds__(256) void bn_apply_f32(
    const float* __restrict__ h2, const float* __restrict__ bns,
    const float* __restrict__ gamma, const float* __restrict__ beta,
    float* __restrict__ xout)
{
    const size_t i = ((size_t)blockIdx.x * 256 + threadIdx.x) * 4;
    if (i >= (size_t)NN * DD) return;
    const int c4 = (int)(i & 127);
    const float4 hv = *(const float4*)&h2[i];
    const float4 sv = *(const float4*)&bns[c4];
    const float4 qv = *(const float4*)&bns[DD + c4];
    const float4 gv = *(const float4*)&gamma[c4];
    const float4 bv = *(const float4*)&beta[c4];
    const float inv_n = 1.f / (float)NN;
    float4 ov;
    { const float m = sv.x * inv_n; const float var = qv.x * inv_n - m * m;
      ov.x = fmaxf((hv.x - m) * __frsqrt_rn(var + BN_EPS) * gv.x + bv.x, 0.f); }
    { const float m = sv.y * inv_n; const float var = qv.y * inv_n - m * m;
      ov.y = fmaxf((hv.y - m) * __frsqrt_rn(var + BN_EPS) * gv.y + bv.y, 0.f); }
    { const float m = sv.z * inv_n; const float var = qv.z * inv_n - m * m;
      ov.z = fmaxf((hv.z - m) * __frsqrt_rn(var + BN_EPS) * gv.z + bv.z, 0.f); }
    { const float m = sv.w * inv_n; const float var = qv.w * inv_n - m * m;
      ov.w = fmaxf((hv.w - m) * __frsqrt_rn(var + BN_EPS) * gv.w + bv.w, 0.f); }
    *(float4*)&xout[i] = ov;
}

extern "C" void kernel_launch(void* const* d_in, const int* in_sizes, int n_in,
                              void* d_out, int out_size, void* d_ws, size_t ws_size,
                              hipStream_t stream) {
    const float* x0    = (const float*)d_in[0];
    const float* ea    = (const float*)d_in[1];
    const int*   eidx  = (const int*)d_in[2];
    const float* We    = (const float*)d_in[3];
    const float* be    = (const float*)d_in[4];
    const float* W1    = (const float*)d_in[5];
    const float* b1    = (const float*)d_in[6];
    const float* W2    = (const float*)d_in[7];
    const float* b2    = (const float*)d_in[8];
    const float* gamma = (const float*)d_in[9];
    const float* beta  = (const float*)d_in[10];
    float* out = (float*)d_out;
    float* ws  = (float*)d_ws;

    float* agg = ws;                              // NN*DD f32 (doubles as h2)
    float* bns = agg + (size_t)NN * DD;           // NL*256
    int* deg      = (int*)(bns + NL * 256);       // 50000
    int* rowptr   = deg + 50000;                  // 50004 (padded, mult of 4)
    int* bsum     = rowptr + 50004;               // 64
    int* rank     = bsum + 64;                    // NE
    int* eid_perm = rank + NE;                    // NE
    unsigned* sd_pk = (unsigned*)(eid_perm + NE); // NE+4 (sentinel; 16B-aligned)
    unsigned short* ea_bf = (unsigned short*)(sd_pk + NE + 4);  // NE*ED
    unsigned short* wt_bf = ea_bf + (size_t)NE * ED;            // NL*DD*ED
    unsigned short* w1t   = wt_bf + (size_t)NL * DD * ED;       // NL*DD*DD
    unsigned short* w2t   = w1t + (size_t)NL * DD * DD;         // NL*DD*DD
    unsigned short* xbf   = w2t + (size_t)NL * DD * DD;         // NN*DD bf16

    const int* esrc = eidx;
    const int* edst = eidx + NE;

    // ---- CSR build + bf16 pre-conversion (once; reused by all 4 layers) ----
    hipMemsetAsync(deg, 0, NN * sizeof(int), stream);
    hipMemsetAsync(bns, 0, NL * 256 * sizeof(float), stream);
    hipMemsetAsync(agg, 0, (size_t)NN * DD * sizeof(float), stream);
    hist_rank_kernel<<<(NE + 255) / 256, 256, 0, stream>>>(edst, deg, rank);
    scan1_kernel<<<NB, 256, 0, stream>>>(deg, rowptr, bsum);
    scan2_kernel<<<1, 64, 0, stream>>>(bsum);
    scan3_kernel<<<(NN + 255) / 256, 256, 0, stream>>>(rowptr, bsum);
    place_kernel<<<(NE + 255) / 256, 256, 0, stream>>>(edst, rowptr, rank, eid_perm);
    sdea_kernel<<<((size_t)NE * 8 + 255) / 256, 256, 0, stream>>>(
        eid_perm, esrc, edst, ea, sd_pk, ea_bf);
    x0conv_kernel<<<((NN * DD / 8) + 255) / 256, 256, 0, stream>>>(x0, xbf);
    wconv_kernel<<<(NL * DD * ED + 255) / 256, 256, 0, stream>>>(We, wt_bf);
    w12conv_kernel<<<(NL * DD * DD + 255) / 256, 256, 0, stream>>>(W1, W2, w1t, w2t);

    for (int l = 0; l < NL; ++l) {
        edge_mfma_kernel<<<NE / EB, 256, 0, stream>>>(
            xbf, ea_bf, sd_pk,
            wt_bf + (size_t)l * DD * ED, be + (size_t)l * DD, agg);
        mlp_mfma_kernel<<<(NN + MR - 1) / MR, 256, 0, stream>>>(
            xbf, agg, agg,
            w1t + (size_t)l * DD * DD, w2t + (size_t)l * DD * DD,
            b1 + (size_t)l * DD, b2 + (size_t)l * DD, bns + l * 256);
        if (l < NL - 1) {
            bn_apply_bf16<<<(NN * DD / 4 + 255) / 256, 256, 0, stream>>>(
                agg, bns + l * 256, gamma + (size_t)l * DD, beta + (size_t)l * DD, xbf);
        } else {
            bn_apply_f32<<<(NN * DD / 4 + 255) / 256, 256, 0, stream>>>(
                agg, bns + l * 256, gamma + (size_t)l * DD, beta + (size_t)l * DD, out);
        }
    }
}